// Round 4
// baseline (178.354 us; speedup 1.0000x reference)
//
#include <hip/hip_runtime.h>

#define BB 4
#define CC 64
#define HH 128
#define WW 256

// One wave = one (b, h, dy). 64 lanes x 4 cols = full W row; 9 dx in regs.
// No LDS, no barriers. Explicit 2-deep register pipeline (batches A/B) keeps
// 4 loads in flight under each 36-FMA compute block; 18 waves/CU for TLP.
__global__ __launch_bounds__(192, 5) void corr_kernel(
    const float* __restrict__ first,
    const float* __restrict__ second,
    float* __restrict__ out)
{
  const int tid  = threadIdx.x;
  const int lane = tid & 63;
  const int wv   = tid >> 6;                 // 0..2 (dy group member)
  // XCD-aware: bid%8 ~ XCD; each XCD owns a contiguous 16-row h band for all
  // b and dy -> second-row re-reads across dy hit the same L2.
  const int bid  = blockIdx.x;
  const int xcd  = bid & 7;
  const int idx  = bid >> 3;                 // 0..191
  const int h    = xcd * 16 + (idx & 15);
  const int rem  = idx >> 4;                 // 0..11
  const int b    = rem & 3;
  const int dy   = (rem >> 2) * 3 + wv;      // 0..8
  const int l4   = lane * 4;

  const size_t plane = (size_t)HH * WW;
  float* obase = out + (((size_t)b * 81 + (size_t)dy * 9) * HH + (size_t)h) * WW + l4;

  const int gh = h + dy - 4;                 // this wave's second row
  if (gh < 0 || gh >= HH) {                  // whole row OOB -> zeros
    const float4 z = make_float4(0.f, 0.f, 0.f, 0.f);
#pragma unroll
    for (int dx = 0; dx < 9; ++dx)
      *(float4*)(obase + (size_t)dx * plane) = z;
    return;
  }

  const float* frow = first  + ((size_t)b * CC * HH + (size_t)h ) * WW + l4;
  const float* srow = second + ((size_t)b * CC * HH + (size_t)gh) * WW;

  // Window cols l4-4..l4+7 = three aligned float4; edge lanes clamp address
  // (stay in-bounds) and zero the value.
  const bool zL = (lane == 0), zR = (lane == 63);
  const int offL = zL ? l4 : l4 - 4;
  const int offR = zR ? l4 : l4 + 4;

  float acc[36];
#pragma unroll
  for (int k = 0; k < 36; ++k) acc[k] = 0.f;

#define LOADS(F, L, M, R, c)                                  \
  do {                                                        \
    const size_t cp = (size_t)(c) * plane;                    \
    F = *(const float4*)(frow + cp);                          \
    L = *(const float4*)(srow + cp + offL);                   \
    M = *(const float4*)(srow + cp + l4);                     \
    R = *(const float4*)(srow + cp + offR);                   \
  } while (0)

#define COMPUTE(F, L, M, R)                                   \
  do {                                                        \
    float4 Lz = L, Rz = R;                                    \
    if (zL) { Lz.x = 0.f; Lz.y = 0.f; Lz.z = 0.f; Lz.w = 0.f; } \
    if (zR) { Rz.x = 0.f; Rz.y = 0.f; Rz.z = 0.f; Rz.w = 0.f; } \
    const float fv[4]  = {F.x, F.y, F.z, F.w};                \
    const float sv[12] = {Lz.x, Lz.y, Lz.z, Lz.w,             \
                          M.x,  M.y,  M.z,  M.w,              \
                          Rz.x, Rz.y, Rz.z, Rz.w};            \
    _Pragma("unroll") for (int dx = 0; dx < 9; ++dx)          \
      _Pragma("unroll") for (int i = 0; i < 4; ++i)           \
        acc[dx * 4 + i] = fmaf(fv[i], sv[i + dx], acc[dx * 4 + i]); \
  } while (0)

  float4 fA, lA, mA, rA, fB, lB, mB, rB;
  LOADS(fA, lA, mA, rA, 0);
  LOADS(fB, lB, mB, rB, 1);

#pragma unroll 1
  for (int c = 0; c < CC; c += 2) {
    COMPUTE(fA, lA, mA, rA);                 // waits A only; B stays in flight
    if (c + 2 < CC) LOADS(fA, lA, mA, rA, c + 2);
    COMPUTE(fB, lB, mB, rB);
    if (c + 3 < CC) LOADS(fB, lB, mB, rB, c + 3);
    // Pin accumulators: forces all 36 chains materialized per iteration,
    // blocking any compiler restructuring of the accumulation.
#pragma unroll
    for (int k = 0; k < 36; ++k) asm("" : "+v"(acc[k]));
  }

  const float sc = 1.0f / (float)CC;
#pragma unroll
  for (int dx = 0; dx < 9; ++dx) {
    float4 v = make_float4(acc[dx * 4 + 0] * sc, acc[dx * 4 + 1] * sc,
                           acc[dx * 4 + 2] * sc, acc[dx * 4 + 3] * sc);
    *(float4*)(obase + (size_t)dx * plane) = v;
  }
#undef LOADS
#undef COMPUTE
}

extern "C" void kernel_launch(void* const* d_in, const int* in_sizes, int n_in,
                              void* d_out, int out_size, void* d_ws, size_t ws_size,
                              hipStream_t stream) {
  const float* first  = (const float*)d_in[0];
  const float* second = (const float*)d_in[1];
  float* out = (float*)d_out;
  (void)in_sizes; (void)n_in; (void)out_size; (void)d_ws; (void)ws_size;
  corr_kernel<<<dim3(8 * 192), dim3(192), 0, stream>>>(first, second, out);
}

// Round 5
// 45.581 us; speedup vs baseline: 3.9129x; 3.9129x over previous
//
#include <hip/hip_runtime.h>

#define HH 128
#define WW 256
#define DEPTH 6          // LDS ring slots per wave; prefetch distance 5 c-pairs
#define NCP 32           // 64 channels -> 32 half2-packed channel-pairs
#define PLANE 32768      // H*W dwords per packed plane
#define PACKED_DWORDS 4194304ull   // 4 b * 32 cp * 32768

typedef unsigned int u32;
typedef _Float16 f16;
typedef f16 f16x2 __attribute__((ext_vector_type(2)));
typedef u32 u32x4 __attribute__((ext_vector_type(4)));

union U32H2 { u32 u; f16x2 h; };

// async global->LDS, 16B/lane: global src per-lane, LDS dest uniform base + lane*16.
__device__ __forceinline__ void gload_lds16(const u32* g, u32* l) {
  __builtin_amdgcn_global_load_lds(
      (const __attribute__((address_space(1))) u32*)g,
      (__attribute__((address_space(3))) u32*)l, 16, 0, 0);
}

__device__ __forceinline__ void waitv(int n) {   // n is compile-time after unroll
  if      (n >= 8) asm volatile("s_waitcnt vmcnt(8)" ::: "memory");
  else if (n == 6) asm volatile("s_waitcnt vmcnt(6)" ::: "memory");
  else if (n == 4) asm volatile("s_waitcnt vmcnt(4)" ::: "memory");
  else if (n == 2) asm volatile("s_waitcnt vmcnt(2)" ::: "memory");
  else             asm volatile("s_waitcnt vmcnt(0)" ::: "memory");
}

// ---- pack: fp32 [b][c][h][w] -> dword=half2(c,c+1) at [b][c/2][h][w] ----
__global__ __launch_bounds__(256) void pack_kernel(
    const float* __restrict__ a, const float* __restrict__ b,
    u32* __restrict__ pa, u32* __restrict__ pb)
{
  int bid = blockIdx.x;
  const float* src = a; u32* dst = pa;
  if (bid >= 4096) { src = b; dst = pb; bid -= 4096; }
  const int di  = bid * 1024 + threadIdx.x * 4;   // packed dword index, 16B-aligned
  const int p   = di & (PLANE - 1);
  const int cpb = di >> 15;                        // b*32 + cp
  const int bI  = cpb >> 5, cp = cpb & 31;
  const size_t s0 = ((size_t)(bI * 64 + cp * 2)) * PLANE + p;
  const float4 x = *(const float4*)(src + s0);
  const float4 y = *(const float4*)(src + s0 + PLANE);
  U32H2 h0, h1, h2, h3;
  h0.h = f16x2{(f16)x.x, (f16)y.x};
  h1.h = f16x2{(f16)x.y, (f16)y.y};
  h2.h = f16x2{(f16)x.z, (f16)y.z};
  h3.h = f16x2{(f16)x.w, (f16)y.w};
  u32x4 o = {h0.u, h1.u, h2.u, h3.u};
  *(u32x4*)(dst + di) = o;
}

// ---- correlation: wave=(b,h,dy), private LDS ring, counted vmcnt, no barriers ----
__global__ __launch_bounds__(256) void corr_f16(
    const u32* __restrict__ pf, const u32* __restrict__ ps,
    float* __restrict__ out)
{
  __shared__ u32 lds[4][DEPTH * 264 + DEPTH * 256];   // 49920 B/block

  const int tid  = threadIdx.x;
  const int lane = tid & 63;
  const int wv   = __builtin_amdgcn_readfirstlane(tid >> 6);  // = b, 0..3
  const int bid  = blockIdx.x;
  const int xcd  = bid & 7;                 // contiguous 16-row h band per XCD
  const int idx  = bid >> 3;                // 0..143
  const int h    = xcd * 16 + (idx & 15);
  const int dy   = idx >> 4;                // 0..8
  const int b    = wv;
  const int l4   = lane * 4;

  float* obase = out + (((size_t)(b * 81 + dy * 9)) * HH + h) * WW + l4;
  const int gh = h + dy - 4;
  if (gh < 0 || gh >= HH) {                 // whole row OOB -> zeros, exit
    const float4 z = make_float4(0.f, 0.f, 0.f, 0.f);
#pragma unroll
    for (int dx = 0; dx < 9; ++dx) *(float4*)(obase + (size_t)dx * PLANE) = z;
    return;
  }

  u32* S = &lds[wv][0];                     // 6 slots x [4 pad | 256 | 4 pad]
  u32* F = &lds[wv][DEPTH * 264];           // 6 slots x 256
  if (lane < DEPTH * 8) {                   // zero S side-pads once (wave-private)
    const int slot = lane >> 3, pd = lane & 7;
    S[slot * 264 + (pd < 4 ? pd : 256 + pd)] = 0;
  }

  const u32* sg = ps + (size_t)(b * NCP) * PLANE + (size_t)gh * WW + l4;
  const u32* fg = pf + (size_t)(b * NCP) * PLANE + (size_t)h  * WW + l4;

  auto stage = [&](int cp) {                // cp is unroll-constant -> %DEPTH folds
    const int slot = cp % DEPTH;
    gload_lds16(sg + (size_t)cp * PLANE, S + slot * 264 + 4);
    gload_lds16(fg + (size_t)cp * PLANE, F + slot * 256);
  };

#pragma unroll
  for (int cp = 0; cp < DEPTH - 1; ++cp) stage(cp);   // 10 loads in flight

  float acc[36];
#pragma unroll
  for (int k = 0; k < 36; ++k) acc[k] = 0.f;

#pragma unroll
  for (int cp = 0; cp < NCP; ++cp) {
    const int rem = NCP - 1 - cp;
    waitv(2 * (rem < 4 ? rem : 4));         // wait cp's 2 loads only; keep 8 in flight
    __builtin_amdgcn_sched_barrier(0);      // no ds_read hoisted above the wait
    const int slot = cp % DEPTH;
    const u32x4 fd = *(const u32x4*)(F + slot * 256 + l4);
    const u32x4 s0 = *(const u32x4*)(S + slot * 264 + l4);       // w-4..w-1 (pads at edge)
    const u32x4 s1 = *(const u32x4*)(S + slot * 264 + l4 + 4);   // w..w+3
    const u32x4 s2 = *(const u32x4*)(S + slot * 264 + l4 + 8);   // w+4..w+7
    if (cp + DEPTH - 1 < NCP) stage(cp + DEPTH - 1);  // overwrites slot consumed at cp-1

    U32H2 f_[4], s_[12];
#pragma unroll
    for (int i = 0; i < 4; ++i) f_[i].u = fd[i];
#pragma unroll
    for (int j = 0; j < 4; ++j) { s_[j].u = s0[j]; s_[j + 4].u = s1[j]; s_[j + 8].u = s2[j]; }
#pragma unroll
    for (int dx = 0; dx < 9; ++dx)
#pragma unroll
      for (int i = 0; i < 4; ++i)
        acc[dx * 4 + i] = __builtin_amdgcn_fdot2(f_[i].h, s_[i + dx].h,
                                                 acc[dx * 4 + i], false);
  }

  const float sc = 1.0f / 64.0f;
#pragma unroll
  for (int dx = 0; dx < 9; ++dx) {
    float4 v = make_float4(acc[dx * 4 + 0] * sc, acc[dx * 4 + 1] * sc,
                           acc[dx * 4 + 2] * sc, acc[dx * 4 + 3] * sc);
    *(float4*)(obase + (size_t)dx * PLANE) = v;
  }
}

// ---- fallback (proven-correct fp32 path) if ws is too small ----
__global__ __launch_bounds__(576) void corr_fp32_fb(
    const float* __restrict__ first, const float* __restrict__ second,
    float* __restrict__ out)
{
  const int tid  = threadIdx.x;
  const int lane = tid & 63;
  const int wv   = tid >> 6;
  const int bid  = blockIdx.x;
  const int idx  = bid >> 3;
  const int h    = (bid & 7) * 16 + (idx & 15);
  const int b    = idx >> 4;
  const int l4   = lane * 4;
  const size_t plane = (size_t)HH * WW;
  float* obase = out + (((size_t)b * 81 + (size_t)wv * 9) * HH + h) * WW + l4;
  const int gh = h + wv - 4;
  if (gh < 0 || gh >= HH) {
    const float4 z = make_float4(0.f, 0.f, 0.f, 0.f);
#pragma unroll
    for (int dx = 0; dx < 9; ++dx) *(float4*)(obase + (size_t)dx * plane) = z;
    return;
  }
  const float* frow = first  + ((size_t)b * 64 * HH + h ) * WW;
  const float* srow = second + ((size_t)b * 64 * HH + gh) * WW;
  const bool zL = (lane == 0), zR = (lane == 63);
  const int offL = zL ? l4 : l4 - 4;
  const int offR = zR ? l4 : l4 + 4;
  float acc[9][4];
#pragma unroll
  for (int dx = 0; dx < 9; ++dx)
#pragma unroll
    for (int i = 0; i < 4; ++i) acc[dx][i] = 0.f;
#pragma unroll 2
  for (int c = 0; c < 64; ++c) {
    const size_t cp = (size_t)c * plane;
    float4 f  = *(const float4*)(frow + cp + l4);
    float4 aL = *(const float4*)(srow + cp + offL);
    float4 aM = *(const float4*)(srow + cp + l4);
    float4 aR = *(const float4*)(srow + cp + offR);
    if (zL) { aL.x = aL.y = aL.z = aL.w = 0.f; }
    if (zR) { aR.x = aR.y = aR.z = aR.w = 0.f; }
    const float fv[4]  = {f.x, f.y, f.z, f.w};
    const float sv[12] = {aL.x, aL.y, aL.z, aL.w, aM.x, aM.y, aM.z, aM.w,
                          aR.x, aR.y, aR.z, aR.w};
#pragma unroll
    for (int dx = 0; dx < 9; ++dx)
#pragma unroll
      for (int i = 0; i < 4; ++i)
        acc[dx][i] = fmaf(fv[i], sv[i + dx], acc[dx][i]);
  }
  const float sc = 1.0f / 64.0f;
#pragma unroll
  for (int dx = 0; dx < 9; ++dx) {
    float4 v = make_float4(acc[dx][0] * sc, acc[dx][1] * sc,
                           acc[dx][2] * sc, acc[dx][3] * sc);
    *(float4*)(obase + (size_t)dx * plane) = v;
  }
}

extern "C" void kernel_launch(void* const* d_in, const int* in_sizes, int n_in,
                              void* d_out, int out_size, void* d_ws, size_t ws_size,
                              hipStream_t stream) {
  const float* first  = (const float*)d_in[0];
  const float* second = (const float*)d_in[1];
  float* out = (float*)d_out;
  (void)in_sizes; (void)n_in; (void)out_size;

  if (ws_size >= 2ull * PACKED_DWORDS * 4ull) {
    u32* pfirst  = (u32*)d_ws;
    u32* psecond = pfirst + PACKED_DWORDS;
    pack_kernel<<<dim3(8192), dim3(256), 0, stream>>>(first, second, pfirst, psecond);
    corr_f16 <<<dim3(1152), dim3(256), 0, stream>>>(pfirst, psecond, out);
  } else {
    corr_fp32_fb<<<dim3(512), dim3(576), 0, stream>>>(first, second, out);
  }
}

// Round 6
// 42.213 us; speedup vs baseline: 4.2251x; 1.0798x over previous
//
#include <hip/hip_runtime.h>

#define HH 128
#define WW 256
#define DEPTH 6          // ring slots per wave; 5 channel-pairs prefetch ahead
#define AHEAD 5
#define NCP 32           // 64 channels -> 32 half2-packed channel-pairs
#define PLANE 32768      // H*W dwords per packed plane
#define PACKED_DWORDS 4194304ull   // 4 b * 32 cp * 32768

typedef unsigned int u32;
typedef _Float16 f16;
typedef f16 f16x2 __attribute__((ext_vector_type(2)));
typedef u32 u32x4 __attribute__((ext_vector_type(4)));

union U32H2 { u32 u; f16x2 h; };

// async global->LDS, 16B/lane: global src per-lane, LDS dest uniform base + lane*16.
__device__ __forceinline__ void gload_lds16(const u32* g, u32* l) {
  __builtin_amdgcn_global_load_lds(
      (const __attribute__((address_space(1))) u32*)g,
      (__attribute__((address_space(3))) u32*)l, 16, 0, 0);
}

__device__ __forceinline__ void waitv(int n) {   // n compile-time after unroll
  if      (n >= 8) asm volatile("s_waitcnt vmcnt(8)" ::: "memory");
  else if (n == 6) asm volatile("s_waitcnt vmcnt(6)" ::: "memory");
  else if (n == 4) asm volatile("s_waitcnt vmcnt(4)" ::: "memory");
  else if (n == 2) asm volatile("s_waitcnt vmcnt(2)" ::: "memory");
  else             asm volatile("s_waitcnt vmcnt(0)" ::: "memory");
}

// ---- pack: fp32 [b][c][h][w] -> dword=half2(c,c+1) at [b][c/2][h][w] ----
__global__ __launch_bounds__(256) void pack_kernel(
    const float* __restrict__ a, const float* __restrict__ b,
    u32* __restrict__ pa, u32* __restrict__ pb)
{
  int bid = blockIdx.x;
  const float* src = a; u32* dst = pa;
  if (bid >= 4096) { src = b; dst = pb; bid -= 4096; }
  const int di  = bid * 1024 + threadIdx.x * 4;   // packed dword index, 16B-aligned
  const int p   = di & (PLANE - 1);
  const int cpb = di >> 15;                        // b*32 + cp
  const int bI  = cpb >> 5, cp = cpb & 31;
  const size_t s0 = ((size_t)(bI * 64 + cp * 2)) * PLANE + p;
  const float4 x = *(const float4*)(src + s0);
  const float4 y = *(const float4*)(src + s0 + PLANE);
  U32H2 h0, h1, h2, h3;
  h0.h = f16x2{(f16)x.x, (f16)y.x};
  h1.h = f16x2{(f16)x.y, (f16)y.y};
  h2.h = f16x2{(f16)x.z, (f16)y.z};
  h3.h = f16x2{(f16)x.w, (f16)y.w};
  u32x4 o = {h0.u, h1.u, h2.u, h3.u};
  *(u32x4*)(dst + di) = o;
}

// ---- correlation: wave=(b,h,dy); S via private LDS ring, F via VGPR ring ----
__global__ __launch_bounds__(256, 4) void corr_f16(
    const u32* __restrict__ pf, const u32* __restrict__ ps,
    float* __restrict__ out)
{
  __shared__ u32 lds[4][DEPTH * 264];              // 25344 B/block

  const int tid  = threadIdx.x;
  const int lane = tid & 63;
  const int wv   = __builtin_amdgcn_readfirstlane(tid >> 6);  // = b, 0..3
  const int bid  = blockIdx.x;
  const int xcd  = bid & 7;                 // contiguous 16-row h band per XCD
  const int idx  = bid >> 3;                // 0..143
  const int h    = xcd * 16 + (idx & 15);
  const int dy   = idx >> 4;                // 0..8
  const int b    = wv;
  const int l4   = lane * 4;

  float* obase = out + (((size_t)(b * 81 + dy * 9)) * HH + h) * WW + l4;
  const int gh = h + dy - 4;
  if (gh < 0 || gh >= HH) {                 // whole row OOB -> zeros, exit
    const float4 z = make_float4(0.f, 0.f, 0.f, 0.f);
#pragma unroll
    for (int dx = 0; dx < 9; ++dx) *(float4*)(obase + (size_t)dx * PLANE) = z;
    return;
  }

  u32* S = &lds[wv][0];                     // 6 slots x [4 pad | 256 | 4 pad]
  if (lane < DEPTH * 8) {                   // zero side-pads once (wave-private)
    const int slot = lane >> 3, pd = lane & 7;
    S[slot * 264 + (pd < 4 ? pd : 256 + pd)] = 0;
  }

  const u32* sg = ps + (size_t)(b * NCP) * PLANE + (size_t)gh * WW + l4;
  const u32* fg = pf + (size_t)(b * NCP) * PLANE + (size_t)h  * WW + l4;

  u32x4 fr[DEPTH];                          // F ring: all indices compile-time

  auto pair = [&](int cp) {                 // issue order fixed: S then F
    const int slot = cp % DEPTH;
    gload_lds16(sg + (size_t)cp * PLANE, S + slot * 264 + 4);
    fr[slot] = *(const u32x4*)(fg + (size_t)cp * PLANE);
  };

#pragma unroll
  for (int cp = 0; cp < AHEAD; ++cp) pair(cp);    // 5 pairs = 10 vmem in flight

  float acc[36];
#pragma unroll
  for (int k = 0; k < 36; ++k) acc[k] = 0.f;

#pragma unroll
  for (int cp = 0; cp < NCP; ++cp) {
    const int rem = NCP - 1 - cp;
    waitv(2 * (rem < 4 ? rem : 4));         // pair(cp) done; later pairs in flight
    __builtin_amdgcn_sched_barrier(0);      // rule 18: no ds_read above the wait
    const int slot = cp % DEPTH;
    const u32x4 s0 = *(const u32x4*)(S + slot * 264 + l4);       // w-4..w-1
    const u32x4 s1 = *(const u32x4*)(S + slot * 264 + l4 + 4);   // w..w+3
    const u32x4 s2 = *(const u32x4*)(S + slot * 264 + l4 + 8);   // w+4..w+7
    const u32x4 fd = fr[slot];
    if (cp + AHEAD < NCP) pair(cp + AHEAD); // after reads(cp): slot (cp-1)%6 free

    U32H2 f_[4], s_[12];
#pragma unroll
    for (int i = 0; i < 4; ++i) f_[i].u = fd[i];
#pragma unroll
    for (int j = 0; j < 4; ++j) { s_[j].u = s0[j]; s_[j + 4].u = s1[j]; s_[j + 8].u = s2[j]; }
#pragma unroll
    for (int dx = 0; dx < 9; ++dx)
#pragma unroll
      for (int i = 0; i < 4; ++i)
        acc[dx * 4 + i] = __builtin_amdgcn_fdot2(f_[i].h, s_[i + dx].h,
                                                 acc[dx * 4 + i], false);
  }

  const float sc = 1.0f / 64.0f;
#pragma unroll
  for (int dx = 0; dx < 9; ++dx) {
    float4 v = make_float4(acc[dx * 4 + 0] * sc, acc[dx * 4 + 1] * sc,
                           acc[dx * 4 + 2] * sc, acc[dx * 4 + 3] * sc);
    *(float4*)(obase + (size_t)dx * PLANE) = v;
  }
}

// ---- fallback (proven-correct fp32 path) if ws is too small ----
__global__ __launch_bounds__(576) void corr_fp32_fb(
    const float* __restrict__ first, const float* __restrict__ second,
    float* __restrict__ out)
{
  const int tid  = threadIdx.x;
  const int lane = tid & 63;
  const int wv   = tid >> 6;
  const int bid  = blockIdx.x;
  const int idx  = bid >> 3;
  const int h    = (bid & 7) * 16 + (idx & 15);
  const int b    = idx >> 4;
  const int l4   = lane * 4;
  const size_t plane = (size_t)HH * WW;
  float* obase = out + (((size_t)b * 81 + (size_t)wv * 9) * HH + h) * WW + l4;
  const int gh = h + wv - 4;
  if (gh < 0 || gh >= HH) {
    const float4 z = make_float4(0.f, 0.f, 0.f, 0.f);
#pragma unroll
    for (int dx = 0; dx < 9; ++dx) *(float4*)(obase + (size_t)dx * plane) = z;
    return;
  }
  const float* frow = first  + ((size_t)b * 64 * HH + h ) * WW;
  const float* srow = second + ((size_t)b * 64 * HH + gh) * WW;
  const bool zL = (lane == 0), zR = (lane == 63);
  const int offL = zL ? l4 : l4 - 4;
  const int offR = zR ? l4 : l4 + 4;
  float acc[9][4];
#pragma unroll
  for (int dx = 0; dx < 9; ++dx)
#pragma unroll
    for (int i = 0; i < 4; ++i) acc[dx][i] = 0.f;
#pragma unroll 2
  for (int c = 0; c < 64; ++c) {
    const size_t cp = (size_t)c * plane;
    float4 f  = *(const float4*)(frow + cp + l4);
    float4 aL = *(const float4*)(srow + cp + offL);
    float4 aM = *(const float4*)(srow + cp + l4);
    float4 aR = *(const float4*)(srow + cp + offR);
    if (zL) { aL.x = aL.y = aL.z = aL.w = 0.f; }
    if (zR) { aR.x = aR.y = aR.z = aR.w = 0.f; }
    const float fv[4]  = {f.x, f.y, f.z, f.w};
    const float sv[12] = {aL.x, aL.y, aL.z, aL.w, aM.x, aM.y, aM.z, aM.w,
                          aR.x, aR.y, aR.z, aR.w};
#pragma unroll
    for (int dx = 0; dx < 9; ++dx)
#pragma unroll
      for (int i = 0; i < 4; ++i)
        acc[dx][i] = fmaf(fv[i], sv[i + dx], acc[dx][i]);
  }
  const float sc = 1.0f / 64.0f;
#pragma unroll
  for (int dx = 0; dx < 9; ++dx) {
    float4 v = make_float4(acc[dx][0] * sc, acc[dx][1] * sc,
                           acc[dx][2] * sc, acc[dx][3] * sc);
    *(float4*)(obase + (size_t)dx * plane) = v;
  }
}

extern "C" void kernel_launch(void* const* d_in, const int* in_sizes, int n_in,
                              void* d_out, int out_size, void* d_ws, size_t ws_size,
                              hipStream_t stream) {
  const float* first  = (const float*)d_in[0];
  const float* second = (const float*)d_in[1];
  float* out = (float*)d_out;
  (void)in_sizes; (void)n_in; (void)out_size;

  if (ws_size >= 2ull * PACKED_DWORDS * 4ull) {
    u32* pfirst  = (u32*)d_ws;
    u32* psecond = pfirst + PACKED_DWORDS;
    pack_kernel<<<dim3(8192), dim3(256), 0, stream>>>(first, second, pfirst, psecond);
    corr_f16 <<<dim3(1152), dim3(256), 0, stream>>>(pfirst, psecond, out);
  } else {
    corr_fp32_fb<<<dim3(512), dim3(576), 0, stream>>>(first, second, out);
  }
}

// Round 8
// 40.575 us; speedup vs baseline: 4.3956x; 1.0404x over previous
//
#include <hip/hip_runtime.h>

#define HH 128
#define WW 256
#define DEPTH 4          // ring slots per wave
#define AHEAD 3          // channel-pairs in flight; drain target = 2*(AHEAD-1)
#define NCP 32           // 64 channels -> 32 half2-packed channel-pairs
#define PLANE 32768      // H*W dwords per packed plane
#define PACKED_DWORDS 4194304ull   // 4 b * 32 cp * 32768

typedef unsigned int u32;
typedef _Float16 f16;
typedef f16 f16x2 __attribute__((ext_vector_type(2)));
typedef u32 u32x4 __attribute__((ext_vector_type(4)));

union U32H2 { u32 u; f16x2 h; };

// async global->LDS, 16B/lane: global src per-lane, LDS dest uniform base + lane*16.
__device__ __forceinline__ void gload_lds16(const u32* g, u32* l) {
  __builtin_amdgcn_global_load_lds(
      (const __attribute__((address_space(1))) u32*)g,
      (__attribute__((address_space(3))) u32*)l, 16, 0, 0);
}

__device__ __forceinline__ void waitv(int n) {   // n compile-time after unroll
  if      (n >= 4) asm volatile("s_waitcnt vmcnt(4)" ::: "memory");
  else if (n == 2) asm volatile("s_waitcnt vmcnt(2)" ::: "memory");
  else             asm volatile("s_waitcnt vmcnt(0)" ::: "memory");
}

// ---- pack: fp32 [b][c][h][w] -> dword=half2(c,c+1) at [b][c/2][h][w] ----
__global__ __launch_bounds__(256) void pack_kernel(
    const float* __restrict__ a, const float* __restrict__ b,
    u32* __restrict__ pa, u32* __restrict__ pb)
{
  int bid = blockIdx.x;
  const float* src = a; u32* dst = pa;
  if (bid >= 4096) { src = b; dst = pb; bid -= 4096; }
  const int di  = bid * 1024 + threadIdx.x * 4;   // packed dword index, 16B-aligned
  const int p   = di & (PLANE - 1);
  const int cpb = di >> 15;                        // b*32 + cp
  const int bI  = cpb >> 5, cp = cpb & 31;
  const size_t s0 = ((size_t)(bI * 64 + cp * 2)) * PLANE + p;
  const float4 x = *(const float4*)(src + s0);
  const float4 y = *(const float4*)(src + s0 + PLANE);
  U32H2 h0, h1, h2, h3;
  h0.h = f16x2{(f16)x.x, (f16)y.x};
  h1.h = f16x2{(f16)x.y, (f16)y.y};
  h2.h = f16x2{(f16)x.z, (f16)y.z};
  h3.h = f16x2{(f16)x.w, (f16)y.w};
  u32x4 o = {h0.u, h1.u, h2.u, h3.u};
  *(u32x4*)(dst + di) = o;
}

// ---- correlation: block=(b,h), 9 dy-waves share F via L1; no barriers ----
__global__ __launch_bounds__(576, 5) void corr_f16(
    const u32* __restrict__ pf, const u32* __restrict__ ps,
    float* __restrict__ out)
{
  __shared__ u32 lds[9][DEPTH * 264];              // 38016 B/block

  const int tid  = threadIdx.x;
  const int lane = tid & 63;
  const int dy   = __builtin_amdgcn_readfirstlane(tid >> 6);  // 0..8, wave-uniform
  const int bid  = blockIdx.x;
  const int xcd  = bid & 7;                 // contiguous 16-row h band per XCD
  const int idx  = bid >> 3;                // 0..63
  const int h    = xcd * 16 + (idx & 15);
  const int b    = idx >> 4;                // 0..3
  const int l4   = lane * 4;

  float* obase = out + (((size_t)(b * 81 + dy * 9)) * HH + h) * WW + l4;
  const int gh = h + dy - 4;
  if (gh < 0 || gh >= HH) {                 // whole row OOB -> zeros, exit
    const float4 z = make_float4(0.f, 0.f, 0.f, 0.f);
#pragma unroll
    for (int dx = 0; dx < 9; ++dx) *(float4*)(obase + (size_t)dx * PLANE) = z;
    return;
  }

  u32* S = &lds[dy][0];                     // 4 slots x [4 pad | 256 | 4 pad]
  if (lane < DEPTH * 8) {                   // zero side-pads once (wave-private)
    const int slot = lane >> 3, pd = lane & 7;
    S[slot * 264 + (pd < 4 ? pd : 256 + pd)] = 0;
  }

  const u32* sg = ps + (size_t)(b * NCP) * PLANE + (size_t)gh * WW + l4;
  const u32* fg = pf + (size_t)(b * NCP) * PLANE + (size_t)h  * WW + l4;

  u32x4 fr[DEPTH];                          // F ring: all indices compile-time

  auto pair = [&](int cp) {                 // issue order fixed: S then F
    const int slot = cp % DEPTH;
    gload_lds16(sg + (size_t)cp * PLANE, S + slot * 264 + 4);
    // All 9 dy-waves of this block load the IDENTICAL F address -> L1 reuse.
    fr[slot] = *(const u32x4*)(fg + (size_t)cp * PLANE);
  };

#pragma unroll
  for (int cp = 0; cp < AHEAD; ++cp) pair(cp);    // 3 pairs = 6 vmem in flight

  float acc[36];
#pragma unroll
  for (int k = 0; k < 36; ++k) acc[k] = 0.f;

#pragma unroll
  for (int cp = 0; cp < NCP; ++cp) {
    const int rem = NCP - 1 - cp;
    // Drain pair cp: leave at most AHEAD-1 pairs (=4 vmem) in flight.
    waitv(2 * (rem < AHEAD - 1 ? rem : AHEAD - 1));
    __builtin_amdgcn_sched_barrier(0);      // rule 18: no ds_read above the wait
    const int slot = cp % DEPTH;
    const u32x4 s0 = *(const u32x4*)(S + slot * 264 + l4);       // w-4..w-1
    const u32x4 s1 = *(const u32x4*)(S + slot * 264 + l4 + 4);   // w..w+3
    const u32x4 s2 = *(const u32x4*)(S + slot * 264 + l4 + 8);   // w+4..w+7
    const u32x4 fd = fr[slot];
    if (cp + AHEAD < NCP) pair(cp + AHEAD); // slot (cp-1)%4 was consumed at cp-1

    U32H2 f_[4], s_[12];
#pragma unroll
    for (int i = 0; i < 4; ++i) f_[i].u = fd[i];
#pragma unroll
    for (int j = 0; j < 4; ++j) { s_[j].u = s0[j]; s_[j + 4].u = s1[j]; s_[j + 8].u = s2[j]; }
#pragma unroll
    for (int dx = 0; dx < 9; ++dx)
#pragma unroll
      for (int i = 0; i < 4; ++i)
        acc[dx * 4 + i] = __builtin_amdgcn_fdot2(f_[i].h, s_[i + dx].h,
                                                 acc[dx * 4 + i], false);
  }

  const float sc = 1.0f / 64.0f;
#pragma unroll
  for (int dx = 0; dx < 9; ++dx) {
    float4 v = make_float4(acc[dx * 4 + 0] * sc, acc[dx * 4 + 1] * sc,
                           acc[dx * 4 + 2] * sc, acc[dx * 4 + 3] * sc);
    *(float4*)(obase + (size_t)dx * PLANE) = v;
  }
}

// ---- fallback (proven-correct fp32 path) if ws is too small ----
__global__ __launch_bounds__(576) void corr_fp32_fb(
    const float* __restrict__ first, const float* __restrict__ second,
    float* __restrict__ out)
{
  const int tid  = threadIdx.x;
  const int lane = tid & 63;
  const int wv   = tid >> 6;
  const int bid  = blockIdx.x;
  const int idx  = bid >> 3;
  const int h    = (bid & 7) * 16 + (idx & 15);
  const int b    = idx >> 4;
  const int l4   = lane * 4;
  const size_t plane = (size_t)HH * WW;
  float* obase = out + (((size_t)b * 81 + (size_t)wv * 9) * HH + h) * WW + l4;
  const int gh = h + wv - 4;
  if (gh < 0 || gh >= HH) {
    const float4 z = make_float4(0.f, 0.f, 0.f, 0.f);
#pragma unroll
    for (int dx = 0; dx < 9; ++dx) *(float4*)(obase + (size_t)dx * plane) = z;
    return;
  }
  const float* frow = first  + ((size_t)b * 64 * HH + h ) * WW;
  const float* srow = second + ((size_t)b * 64 * HH + gh) * WW;
  const bool zL = (lane == 0), zR = (lane == 63);
  const int offL = zL ? l4 : l4 - 4;
  const int offR = zR ? l4 : l4 + 4;
  float acc[9][4];
#pragma unroll
  for (int dx = 0; dx < 9; ++dx)
#pragma unroll
    for (int i = 0; i < 4; ++i) acc[dx][i] = 0.f;
#pragma unroll 2
  for (int c = 0; c < 64; ++c) {
    const size_t cp = (size_t)c * plane;
    float4 f  = *(const float4*)(frow + cp + l4);
    float4 aL = *(const float4*)(srow + cp + offL);
    float4 aM = *(const float4*)(srow + cp + l4);
    float4 aR = *(const float4*)(srow + cp + offR);
    if (zL) { aL.x = aL.y = aL.z = aL.w = 0.f; }
    if (zR) { aR.x = aR.y = aR.z = aR.w = 0.f; }
    const float fv[4]  = {f.x, f.y, f.z, f.w};
    const float sv[12] = {aL.x, aL.y, aL.z, aL.w, aM.x, aM.y, aM.z, aM.w,
                          aR.x, aR.y, aR.z, aR.w};
#pragma unroll
    for (int dx = 0; dx < 9; ++dx)
#pragma unroll
      for (int i = 0; i < 4; ++i)
        acc[dx][i] = fmaf(fv[i], sv[i + dx], acc[dx][i]);
  }
  const float sc = 1.0f / 64.0f;
#pragma unroll
  for (int dx = 0; dx < 9; ++dx) {
    float4 v = make_float4(acc[dx][0] * sc, acc[dx][1] * sc,
                           acc[dx][2] * sc, acc[dx][3] * sc);
    *(float4*)(obase + (size_t)dx * plane) = v;
  }
}

extern "C" void kernel_launch(void* const* d_in, const int* in_sizes, int n_in,
                              void* d_out, int out_size, void* d_ws, size_t ws_size,
                              hipStream_t stream) {
  const float* first  = (const float*)d_in[0];
  const float* second = (const float*)d_in[1];
  float* out = (float*)d_out;
  (void)in_sizes; (void)n_in; (void)out_size;

  if (ws_size >= 2ull * PACKED_DWORDS * 4ull) {
    u32* pfirst  = (u32*)d_ws;
    u32* psecond = pfirst + PACKED_DWORDS;
    pack_kernel<<<dim3(8192), dim3(256), 0, stream>>>(first, second, pfirst, psecond);
    corr_f16 <<<dim3(512), dim3(576), 0, stream>>>(pfirst, psecond, out);
  } else {
    corr_fp32_fb<<<dim3(512), dim3(576), 0, stream>>>(first, second, out);
  }
}